// Round 12
// baseline (95.470 us; speedup 1.0000x reference)
//
#include <hip/hip_runtime.h>
#include <hip/hip_bf16.h>

#define D_ 256
#define HW_ 1024

typedef short short4v __attribute__((ext_vector_type(4)));
typedef short short8 __attribute__((ext_vector_type(8)));
typedef float float4v __attribute__((ext_vector_type(4)));

__device__ __forceinline__ unsigned short f2bf(float f) {
  unsigned u = __builtin_bit_cast(unsigned, f);
  return (unsigned short)((u + 0x7fffu + ((u >> 16) & 1u)) >> 16);
}
__device__ __forceinline__ float bf2f(unsigned short h) {
  return __builtin_bit_cast(float, ((unsigned)h) << 16);
}
__device__ __forceinline__ void async16(void* lds, const void* g) {
  __builtin_amdgcn_global_load_lds(
      (__attribute__((address_space(1))) const unsigned int*)g,
      (__attribute__((address_space(3))) unsigned int*)lds, 16, 0, 0);
}

// ---- prep: cnorm + bf16(-2c) in MFMA A-fragment order (proven R9/R10) ----
__global__ __launch_bounds__(256) void vq_prep(const float* __restrict__ cb,
                                               unsigned short* __restrict__ cbfrag,
                                               float* __restrict__ cnorm) {
  int k = blockIdx.x;   // code 0..1023
  int t = threadIdx.x;  // feature 0..255
  float c = cb[k * D_ + t];
  float s = c * c;
#pragma unroll
  for (int off = 1; off < 64; off <<= 1) s += __shfl_xor(s, off, 64);
  __shared__ float wsum[4];
  if ((t & 63) == 0) wsum[t >> 6] = s;
  __syncthreads();
  if (t == 0) cnorm[k] = wsum[0] + wsum[1] + wsum[2] + wsum[3];
  int g = k >> 4, cc = k & 15;
  int kk = t >> 5, q = (t >> 3) & 3, e = t & 7;
  cbfrag[(((g * 8) + kk) * 64 + q * 16 + cc) * 8 + e] = f2bf(-2.0f * c);
}

// ---- partial: per code-quarter distance+argmin (split-K over codes) ----
// grid 2048 = quarter(4) x pgroup(512); 256 thr (2 pg x 2 ch); 128 pts/block.
// Per-point (minD, minI) partials stored in d_out rows 0..7 of each block's
// own output region (read-then-overwritten by vq_merge_gather, same block).
__global__ __launch_bounds__(256) void vq_partial(const float* __restrict__ lat,
                                                  const short8* __restrict__ cbfrag,
                                                  const float* __restrict__ cnorm,
                                                  float* __restrict__ outsc,
                                                  float* __restrict__ part) {
  // [0,49152) 3x16KB slots (stage img overlays [0,32768)); [49152,50176) cnorm_s;
  // [50176,50688) mergeD; [50688,51200) mergeI
  __shared__ __align__(16) char smem[51200];
  short8* slots = (short8*)smem;
  unsigned short* img = (unsigned short*)smem;
  float* cnorm_s = (float*)(smem + 49152);
  float* mergeD = (float*)(smem + 50176);
  int* mergeI = (int*)(smem + 50688);

  const int tid = threadIdx.x;
  const int w = tid >> 6, lane = tid & 63;
  const int pg = w >> 1, ch = w & 1;
  const int q = lane >> 4, c = lane & 15;
  const int quarter = blockIdx.x >> 9;
  const int pgrp = blockIdx.x & 511;
  const int b = pgrp >> 3, hwb = (pgrp & 7) << 7;
  const int qbase = quarter * 256;
  const short8* cbq = cbfrag + quarter * 8192;  // 256 codes = 8192 short8

  cnorm_s[tid] = cnorm[qbase + tid];

  // ---- stage points tile-by-tile (proven R10 pattern) ----
  short8 bfrag[4][8];
  float fn[4];
#pragma unroll 1
  for (int t = 0; t < 2; ++t) {
#pragma unroll 4
    for (int jj = 0; jj < 8; ++jj) {
      int j = w * 8 + jj;
      short8 v;
#pragma unroll
      for (int e = 0; e < 8; ++e) {
        float f = lat[((size_t)(b * D_ + j * 8 + e)) * HW_ + hwb + t * 64 + lane];
        v[e] = (short)f2bf(f);
      }
      *(short8*)&img[lane * 256 + ((j * 8) ^ ((lane & 15) << 4))] = v;
    }
    __syncthreads();
    if (pg == t) {
#pragma unroll
      for (int pf = 0; pf < 4; ++pf) {
        int row = pf * 16 + c;
#pragma unroll
        for (int kk = 0; kk < 8; ++kk) {
          int s = (kk << 2) | q;
          bfrag[pf][kk] =
              *(const short8*)&img[row * 256 + ((s * 8) ^ ((row & 15) << 4))];
        }
        float a = 0.f;
#pragma unroll
        for (int kk = 0; kk < 8; ++kk)
#pragma unroll
          for (int e = 0; e < 8; ++e) {
            float f = bf2f((unsigned short)bfrag[pf][kk][e]);
            a += f * f;
          }
        fn[pf] = a;
      }
#pragma unroll
      for (int pf = 0; pf < 4; ++pf) {
        fn[pf] += __shfl_xor(fn[pf], 16, 64);
        fn[pf] += __shfl_xor(fn[pf], 32, 64);
      }
    }
    __syncthreads();  // drains everything: clean slate for vmcnt counting
  }

  // ---- prologue: chunks 0,1 -> slots 0,1 ----
#pragma unroll
  for (int ck = 0; ck < 2; ++ck)
#pragma unroll
    for (int r = 0; r < 4; ++r)
      async16(&slots[ck * 1024 + r * 256 + tid], cbq + (ck * 1024 + r * 256 + tid));

  float runD[4];
  int runI[4];
#pragma unroll
  for (int pf = 0; pf < 4; ++pf) { runD[pf] = 3.0e38f; runI[pf] = 0x7fffffff; }

  // ---- 8 chunks; wait(4) -> barrier -> issue i+2 -> MFMA -> scan ----
#pragma unroll 1
  for (int i = 0; i < 8; ++i) {
    if (i < 7) asm volatile("s_waitcnt vmcnt(4)" ::: "memory");
    else asm volatile("s_waitcnt vmcnt(0)" ::: "memory");
    __builtin_amdgcn_s_barrier();
    __builtin_amdgcn_sched_barrier(0);
    if (i < 6) {
      int ck = i + 2;
      short8* dst = &slots[(ck % 3) * 1024];
      const short8* src = cbq + ck * 1024;
#pragma unroll
      for (int r = 0; r < 4; ++r) async16(&dst[r * 256 + tid], src + r * 256 + tid);
    }
    float4v cn = *(const float4v*)&cnorm_s[i * 32 + ch * 16 + q * 4];
    float4v acc[4];
#pragma unroll
    for (int pf = 0; pf < 4; ++pf) acc[pf] = cn;
    const short8* slot = &slots[(i % 3) * 1024];
    __builtin_amdgcn_s_setprio(1);
#pragma unroll
    for (int kk = 0; kk < 8; ++kk) {
      short8 afr = slot[(ch * 8 + kk) * 64 + lane];
#pragma unroll
      for (int pf = 0; pf < 4; ++pf)
        acc[pf] = __builtin_amdgcn_mfma_f32_16x16x32_bf16(afr, bfrag[pf][kk],
                                                          acc[pf], 0, 0, 0);
    }
    __builtin_amdgcn_s_setprio(0);
    // lane-local scan (ascending code index; strict < = first occurrence)
#pragma unroll
    for (int pf = 0; pf < 4; ++pf) {
      int cb0 = qbase + i * 32 + ch * 16 + q * 4;
#pragma unroll
      for (int r = 0; r < 4; ++r) {
        float dv = acc[pf][r];
        if (dv < runD[pf]) { runD[pf] = dv; runI[pf] = cb0 + r; }
      }
    }
  }

  // ---- butterfly + ch-merge; write per-point partials into out-scratch ----
#pragma unroll
  for (int pf = 0; pf < 4; ++pf) {
#pragma unroll
    for (int di = 16; di < 64; di <<= 1) {
      float od = __shfl_xor(runD[pf], di, 64);
      int oi = __shfl_xor(runI[pf], di, 64);
      if (od < runD[pf] || (od == runD[pf] && oi < runI[pf])) {
        runD[pf] = od; runI[pf] = oi;
      }
    }
  }
  float selD = q == 0 ? runD[0] : q == 1 ? runD[1] : q == 2 ? runD[2] : runD[3];
  int selI = q == 0 ? runI[0] : q == 1 ? runI[1] : q == 2 ? runI[2] : runI[3];
  int p = pg * 64 + lane;  // q*16+c == lane
  if (ch == 1) { mergeD[p] = selD; mergeI[p] = selI; }
  __syncthreads();
  if (ch == 0) {
    float od = mergeD[p];
    int oi = mergeI[p];
    if (od < selD || (od == selD && oi < selI)) { selD = od; selI = oi; }
    const size_t base = (size_t)b * D_ * HW_ + hwb + p;
    outsc[base + (size_t)quarter * HW_] = selD;
    outsc[base + (size_t)(4 + quarter) * HW_] = __builtin_bit_cast(float, selI);
    if (quarter == 0) {
      // block-sum of |f|^2 (loss separates: sum fn independent of argmin)
      float s0 = fn[0] + fn[1] + fn[2] + fn[3];
#pragma unroll
      for (int off = 1; off < 16; off <<= 1) s0 += __shfl_xor(s0, off, 64);
      if (lane == 0) part[pgrp * 2 + pg] = s0;
    }
  }
}

// ---- merge partials + loss + gather (R9's proven gather body) ----
// 1024 blocks x 256 thr, 64 pts/block, 4 blocks/CU.
__global__ __launch_bounds__(256) void vq_merge_gather(
    const float* __restrict__ cb, float* __restrict__ out,
    float* __restrict__ part) {
  __shared__ unsigned short gimg[16384];  // 64 rows x 512B, swizzled
  __shared__ int sidx[64];
  const int tid = threadIdx.x;
  const int w = tid >> 6, lane = tid & 63;
  const int pt0 = blockIdx.x * 64;
  const int b = pt0 >> 10, hw0 = pt0 & 1023;
  if (tid < 64) {
    const size_t base = (size_t)b * D_ * HW_ + hw0 + tid;
    float d = out[base];
    int ix = __builtin_bit_cast(int, out[base + 4 * HW_]);
#pragma unroll
    for (int qq = 1; qq < 4; ++qq) {  // quarters ascend in code idx: strict <
      float d2 = out[base + (size_t)qq * HW_];
      if (d2 < d) { d = d2; ix = __builtin_bit_cast(int, out[base + (size_t)(4 + qq) * HW_]); }
    }
    sidx[tid] = ix;
#pragma unroll
    for (int off = 1; off < 64; off <<= 1) d += __shfl_xor(d, off, 64);
    if (tid == 0) part[1024 + blockIdx.x] = d;  // block-sum of min rel-dist
  }
  __syncthreads();
  // cooperative whole-row reads (1KB float4/instr), bf16 to swizzled LDS
#pragma unroll 4
  for (int rp = 0; rp < 16; ++rp) {
    int row = rp * 4 + w;
    int gidx = sidx[row];
    float4v cv = ((const float4v*)(cb + (size_t)gidx * D_))[lane];
    short4v sv;
#pragma unroll
    for (int i = 0; i < 4; ++i) sv[i] = (short)f2bf(cv[i]);
    *(short4v*)&gimg[row * 256 + ((lane * 4) ^ ((row & 15) << 4))] = sv;
  }
  __syncthreads();
  // coalesced [B,D,H,W] stores (overwrites the scratch rows too)
#pragma unroll
  for (int jo = 0; jo < 8; ++jo) {
    int j = w * 8 + jo;
    short8 v = *(const short8*)&gimg[lane * 256 + ((j * 8) ^ ((lane & 15) << 4))];
#pragma unroll
    for (int e = 0; e < 8; ++e)
      out[((size_t)(b * D_ + j * 8 + e)) * HW_ + hw0 + lane] =
          bf2f((unsigned short)v[e]);
  }
}

// ---- finalize: loss = 1.25*(sum fn + sum minD)/N*D over 2048 partials ----
__global__ __launch_bounds__(256) void vq_fin(const float* __restrict__ part,
                                              float* __restrict__ outs) {
  int t = threadIdx.x;
  float s = 0.f;
#pragma unroll
  for (int k = 0; k < 8; ++k) s += part[t + k * 256];
#pragma unroll
  for (int off = 1; off < 64; off <<= 1) s += __shfl_xor(s, off, 64);
  __shared__ float w4[4];
  if ((t & 63) == 0) w4[t >> 6] = s;
  __syncthreads();
  if (t == 0) *outs = (w4[0] + w4[1] + w4[2] + w4[3]) * (1.25f / 16777216.0f);
}

extern "C" void kernel_launch(void* const* d_in, const int* in_sizes, int n_in,
                              void* d_out, int out_size, void* d_ws, size_t ws_size,
                              hipStream_t stream) {
  const float* lat = (const float*)d_in[0];
  const float* cb = (const float*)d_in[1];
  float* out = (float*)d_out;
  char* ws = (char*)d_ws;
  unsigned short* cbfrag = (unsigned short*)ws;  // 512 KB (bf16 -2c frag image)
  float* cnorm = (float*)(ws + 524288);          // 4 KB
  float* partial = (float*)(ws + 528384);        // 8 KB (2048: fn + minD sums)

  vq_prep<<<1024, 256, 0, stream>>>(cb, cbfrag, cnorm);
  vq_partial<<<2048, 256, 0, stream>>>(lat, (const short8*)cbfrag, cnorm, out,
                                       partial);
  vq_merge_gather<<<1024, 256, 0, stream>>>(cb, out, partial);
  vq_fin<<<1, 256, 0, stream>>>(partial, out + 16777216);
}

// Round 14
// 74.788 us; speedup vs baseline: 1.2765x; 1.2765x over previous
//
#include <hip/hip_runtime.h>
#include <hip/hip_bf16.h>

#define D_ 256
#define HW_ 1024

typedef short short4v __attribute__((ext_vector_type(4)));
typedef short short8 __attribute__((ext_vector_type(8)));
typedef float float4v __attribute__((ext_vector_type(4)));

__device__ __forceinline__ unsigned short f2bf(float f) {
  unsigned u = __builtin_bit_cast(unsigned, f);
  return (unsigned short)((u + 0x7fffu + ((u >> 16) & 1u)) >> 16);
}
__device__ __forceinline__ float bf2f(unsigned short h) {
  return __builtin_bit_cast(float, ((unsigned)h) << 16);
}
__device__ __forceinline__ void async16(void* lds, const void* g) {
  __builtin_amdgcn_global_load_lds(
      (__attribute__((address_space(1))) const unsigned int*)g,
      (__attribute__((address_space(3))) unsigned int*)lds, 16, 0, 0);
}

// ---- prep: cnorm + bf16(-2c) in MFMA A-fragment order (proven R9/R10) ----
__global__ __launch_bounds__(256) void vq_prep(const float* __restrict__ cb,
                                               unsigned short* __restrict__ cbfrag,
                                               float* __restrict__ cnorm) {
  int k = blockIdx.x;   // code 0..1023
  int t = threadIdx.x;  // feature 0..255
  float c = cb[k * D_ + t];
  float s = c * c;
#pragma unroll
  for (int off = 1; off < 64; off <<= 1) s += __shfl_xor(s, off, 64);
  __shared__ float wsum[4];
  if ((t & 63) == 0) wsum[t >> 6] = s;
  __syncthreads();
  if (t == 0) cnorm[k] = wsum[0] + wsum[1] + wsum[2] + wsum[3];
  int g = k >> 4, cc = k & 15;
  int kk = t >> 5, q = (t >> 3) & 3, e = t & 7;
  cbfrag[(((g * 8) + kk) * 64 + q * 16 + cc) * 8 + e] = f2bf(-2.0f * c);
}

// ---- main: 1 block/CU, 8 waves; stage + pipelined loop + argmin + gather ----
// grid 256 x 512 thr (4 pg x 2 ch), 256 pts/block.
__global__ __launch_bounds__(512) void vq_main(const float* __restrict__ lat,
                                               const short8* __restrict__ cbfrag,
                                               const float* __restrict__ cnorm,
                                               const float* __restrict__ cb,
                                               float* __restrict__ out,
                                               float* __restrict__ part) {
  // byte-audited layout (total 89088 B => 1 block/CU):
  //  [0,49152)      3 x 16KB chunk slots
  //  [49152,81920)  img: 64 rows x 512B (32KB)  -- staging/gather tile
  //  [81920,86016)  cnorm_s (4KB)
  //  [86016,87040)  mergeD   [87040,88064) mergeI   [88064,89088) idx_s
  __shared__ __align__(16) char smem[89088];
  short8* slots = (short8*)smem;
  unsigned short* img = (unsigned short*)(smem + 49152);
  float* cnorm_s = (float*)(smem + 81920);
  float* mergeD = (float*)(smem + 86016);
  int* mergeI = (int*)(smem + 87040);
  int* idx_s = (int*)(smem + 88064);

  const int tid = threadIdx.x;  // 0..511
  const int w = tid >> 6, lane = tid & 63;
  const int pg = w >> 1, ch = w & 1;
  const int q = lane >> 4, c = lane & 15;
  const int blk = blockIdx.x;
  const int b = blk >> 2, hwb = (blk & 3) << 8;  // 256 pts/block

  // ---- issue codebook chunks 0,1 immediately (fill hidden under staging) ----
#pragma unroll
  for (int ck = 0; ck < 2; ++ck)
#pragma unroll
    for (int r = 0; r < 2; ++r)
      async16(&slots[ck * 1024 + r * 512 + tid], cbfrag + (ck * 1024 + r * 512 + tid));

  cnorm_s[tid] = cnorm[tid];
  cnorm_s[tid + 512] = cnorm[tid + 512];

  // ---- stage 4 tiles of 64 pts; waves with pg==t extract tile t ----
  short8 bfrag[4][8];
  float fn[4];
#pragma unroll 1
  for (int t = 0; t < 4; ++t) {
#pragma unroll
    for (int jj = 0; jj < 4; ++jj) {
      int j = w * 4 + jj;  // feature octet (8 waves x 4 = 32 octets = 256 feats)
      short8 v;
#pragma unroll
      for (int e = 0; e < 8; ++e) {
        float f = lat[((size_t)(b * D_ + j * 8 + e)) * HW_ + hwb + t * 64 + lane];
        v[e] = (short)f2bf(f);
      }
      *(short8*)&img[lane * 256 + ((j * 8) ^ ((lane & 15) << 4))] = v;
    }
    __syncthreads();
    if (pg == t) {
#pragma unroll
      for (int pf = 0; pf < 4; ++pf) {
        int row = pf * 16 + c;
#pragma unroll
        for (int kk = 0; kk < 8; ++kk) {
          int s = (kk << 2) | q;
          bfrag[pf][kk] =
              *(const short8*)&img[row * 256 + ((s * 8) ^ ((row & 15) << 4))];
        }
        float a = 0.f;
#pragma unroll
        for (int kk = 0; kk < 8; ++kk)
#pragma unroll
          for (int e = 0; e < 8; ++e) {
            float f = bf2f((unsigned short)bfrag[pf][kk][e]);
            a += f * f;
          }
        fn[pf] = a;
      }
#pragma unroll
      for (int pf = 0; pf < 4; ++pf) {
        fn[pf] += __shfl_xor(fn[pf], 16, 64);
        fn[pf] += __shfl_xor(fn[pf], 32, 64);
      }
    }
    __syncthreads();
  }
  // chunks 0,1 arrived; vmcnt drained to 0 by the syncthreads above.

  float runD[4];
  int runI[4];
#pragma unroll
  for (int pf = 0; pf < 4; ++pf) { runD[pf] = 3.0e38f; runI[pf] = 0x7fffffff; }

  // ---- 32 chunks; wait vmcnt(2) -> barrier -> issue i+2 -> MFMA -> scan ----
  // (2 asyncs/chunk/wave: steady outstanding=4; vmcnt(2) completes chunk i,
  //  leaves chunk i+1 in flight)
#pragma unroll 1
  for (int i = 0; i < 32; ++i) {
    if (i < 31) asm volatile("s_waitcnt vmcnt(2)" ::: "memory");
    else asm volatile("s_waitcnt vmcnt(0)" ::: "memory");
    __builtin_amdgcn_s_barrier();
    __builtin_amdgcn_sched_barrier(0);
    if (i < 30) {  // slot (i+2)%3 == (i-1)%3: its readers passed barrier-i
      int ck = i + 2;
      short8* dst = &slots[(ck % 3) * 1024];
      const short8* src = cbfrag + ck * 1024;
#pragma unroll
      for (int r = 0; r < 2; ++r) async16(&dst[r * 512 + tid], src + r * 512 + tid);
    }
    float4v cn = *(const float4v*)&cnorm_s[i * 32 + ch * 16 + q * 4];
    float4v acc[4];
#pragma unroll
    for (int pf = 0; pf < 4; ++pf) acc[pf] = cn;
    const short8* slot = &slots[(i % 3) * 1024];
    __builtin_amdgcn_s_setprio(1);
#pragma unroll
    for (int kk = 0; kk < 8; ++kk) {
      short8 afr = slot[(ch * 8 + kk) * 64 + lane];
#pragma unroll
      for (int pf = 0; pf < 4; ++pf)
        acc[pf] = __builtin_amdgcn_mfma_f32_16x16x32_bf16(afr, bfrag[pf][kk],
                                                          acc[pf], 0, 0, 0);
    }
    __builtin_amdgcn_s_setprio(0);
    // lane-local scan (ascending code index; strict < = first occurrence)
#pragma unroll
    for (int pf = 0; pf < 4; ++pf) {
      int cb0 = i * 32 + ch * 16 + q * 4;
#pragma unroll
      for (int r = 0; r < 4; ++r) {
        float dv = acc[pf][r];
        if (dv < runD[pf]) { runD[pf] = dv; runI[pf] = cb0 + r; }
      }
    }
  }

  // ---- deferred butterfly + ch-merge; idx to LDS; loss partial ----
#pragma unroll
  for (int pf = 0; pf < 4; ++pf) {
#pragma unroll
    for (int di = 16; di < 64; di <<= 1) {
      float od = __shfl_xor(runD[pf], di, 64);
      int oi = __shfl_xor(runI[pf], di, 64);
      if (od < runD[pf] || (od == runD[pf] && oi < runI[pf])) {
        runD[pf] = od; runI[pf] = oi;
      }
    }
  }
  float selD = q == 0 ? runD[0] : q == 1 ? runD[1] : q == 2 ? runD[2] : runD[3];
  int selI = q == 0 ? runI[0] : q == 1 ? runI[1] : q == 2 ? runI[2] : runI[3];
  float selF = q == 0 ? fn[0] : q == 1 ? fn[1] : q == 2 ? fn[2] : fn[3];
  int p = pg * 64 + lane;  // q*16+c == lane
  if (ch == 1) { mergeD[p] = selD; mergeI[p] = selI; }
  __syncthreads();
  if (ch == 0) {
    float od = mergeD[p];
    int oi = mergeI[p];
    if (od < selD || (od == selD && oi < selI)) { selD = od; selI = oi; }
    idx_s[p] = selI;
    float lv = selD + selF;  // ||f - c_best||^2
#pragma unroll
    for (int off = 1; off < 64; off <<= 1) lv += __shfl_xor(lv, off, 64);
    if (lane == 0) part[blk * 4 + pg] = lv;
  }
  __syncthreads();

  // ---- fused gather, 4 sub-tiles: cooperative whole-row reads (1KB/instr) ----
#pragma unroll 1
  for (int st = 0; st < 4; ++st) {
#pragma unroll
    for (int rp = 0; rp < 8; ++rp) {
      int row = rp * 8 + w;
      int gidx = idx_s[st * 64 + row];
      float4v cv = ((const float4v*)(cb + (size_t)gidx * D_))[lane];
      short4v sv;
#pragma unroll
      for (int i = 0; i < 4; ++i) sv[i] = (short)f2bf(cv[i]);
      *(short4v*)&img[row * 256 + ((lane * 4) ^ ((row & 15) << 4))] = sv;
    }
    __syncthreads();
#pragma unroll
    for (int jo = 0; jo < 4; ++jo) {
      int j = w * 4 + jo;
      short8 v = *(const short8*)&img[lane * 256 + ((j * 8) ^ ((lane & 15) << 4))];
#pragma unroll
      for (int e = 0; e < 8; ++e)
        out[((size_t)(b * D_ + j * 8 + e)) * HW_ + hwb + st * 64 + lane] =
            bf2f((unsigned short)v[e]);
    }
    __syncthreads();
  }
}

// ---- finalize: loss = 1.25 * mean (1024 partials) ----
__global__ __launch_bounds__(256) void vq_fin(const float* __restrict__ part,
                                              float* __restrict__ outs) {
  int t = threadIdx.x;
  float s = part[t] + part[t + 256] + part[t + 512] + part[t + 768];
#pragma unroll
  for (int off = 1; off < 64; off <<= 1) s += __shfl_xor(s, off, 64);
  __shared__ float w4[4];
  if ((t & 63) == 0) w4[t >> 6] = s;
  __syncthreads();
  if (t == 0) *outs = (w4[0] + w4[1] + w4[2] + w4[3]) * (1.25f / 16777216.0f);
}

extern "C" void kernel_launch(void* const* d_in, const int* in_sizes, int n_in,
                              void* d_out, int out_size, void* d_ws, size_t ws_size,
                              hipStream_t stream) {
  const float* lat = (const float*)d_in[0];
  const float* cb = (const float*)d_in[1];
  float* out = (float*)d_out;
  char* ws = (char*)d_ws;
  unsigned short* cbfrag = (unsigned short*)ws;  // 512 KB (bf16 -2c frag image)
  float* cnorm = (float*)(ws + 524288);          // 4 KB
  float* partial = (float*)(ws + 528384);        // 4 KB (1024 partials)

  vq_prep<<<1024, 256, 0, stream>>>(cb, cbfrag, cnorm);
  vq_main<<<256, 512, 0, stream>>>(lat, (const short8*)cbfrag, cnorm, cb, out,
                                   partial);
  vq_fin<<<1, 256, 0, stream>>>(partial, out + 16777216);
}

// Round 15
// 67.290 us; speedup vs baseline: 1.4188x; 1.1114x over previous
//
#include <hip/hip_runtime.h>
#include <hip/hip_bf16.h>

#define D_ 256
#define HW_ 1024

typedef short short4v __attribute__((ext_vector_type(4)));
typedef short short8 __attribute__((ext_vector_type(8)));
typedef float float4v __attribute__((ext_vector_type(4)));

__device__ __forceinline__ unsigned short f2bf(float f) {
  unsigned u = __builtin_bit_cast(unsigned, f);
  return (unsigned short)((u + 0x7fffu + ((u >> 16) & 1u)) >> 16);
}
__device__ __forceinline__ float bf2f(unsigned short h) {
  return __builtin_bit_cast(float, ((unsigned)h) << 16);
}
__device__ __forceinline__ void async16(void* lds, const void* g) {
  __builtin_amdgcn_global_load_lds(
      (__attribute__((address_space(1))) const unsigned int*)g,
      (__attribute__((address_space(3))) unsigned int*)lds, 16, 0, 0);
}

// ---- prep: cnorm + bf16(-2c) in MFMA A-fragment order (proven R9) ----
// cbfrag[((g*8)+kk)*64 + q*16 + cc] (short8) = code g*16+cc, feats kk*32+q*8..+7
__global__ __launch_bounds__(256) void vq_prep(const float* __restrict__ cb,
                                               unsigned short* __restrict__ cbfrag,
                                               float* __restrict__ cnorm) {
  int k = blockIdx.x;   // code 0..1023
  int t = threadIdx.x;  // feature 0..255
  float c = cb[k * D_ + t];
  float s = c * c;
#pragma unroll
  for (int off = 1; off < 64; off <<= 1) s += __shfl_xor(s, off, 64);
  __shared__ float wsum[4];
  if ((t & 63) == 0) wsum[t >> 6] = s;
  __syncthreads();
  if (t == 0) cnorm[k] = wsum[0] + wsum[1] + wsum[2] + wsum[3];
  int g = k >> 4, cc = k & 15;
  int kk = t >> 5, q = (t >> 3) & 3, e = t & 7;
  cbfrag[(((g * 8) + kk) * 64 + q * 16 + cc) * 8 + e] = f2bf(-2.0f * c);
}

// ---- main: R9 structure, 2 chunks per barrier (16 iters of 64 codes) ----
// 512 blocks x 256 thr (4 waves = 2 pg x 2 ch), 128 pts/block, 2 blocks/CU.
__global__ __launch_bounds__(256) void vq_main(const float* __restrict__ lat,
                                               const short8* __restrict__ cbfrag,
                                               const float* __restrict__ cnorm,
                                               int* __restrict__ idx_out,
                                               float* __restrict__ part) {
  __shared__ short8 slots[4][1024];   // 64KB: stage img overlay, then 2 pair-sets
  __shared__ float cnorm_s[1024];     // 4KB
  __shared__ float mergeD[128];
  __shared__ int mergeI[128];

  const int tid = threadIdx.x;
  const int w = tid >> 6, lane = tid & 63;
  const int pg = w >> 1, ch = w & 1;
  const int q = lane >> 4, c = lane & 15;
  const int blk = blockIdx.x;
  const int b = blk >> 3, hwb = (blk & 7) << 7;

  cnorm_s[tid] = cnorm[tid];
  cnorm_s[tid + 256] = cnorm[tid + 256];
  cnorm_s[tid + 512] = cnorm[tid + 512];
  cnorm_s[tid + 768] = cnorm[tid + 768];

  // ---- stage 128 pts (proven pattern: coalesced loads, b128 swizzled) ----
  unsigned short* img = (unsigned short*)&slots[0][0];  // 128 rows x 512B
#pragma unroll 1
  for (int t = 0; t < 2; ++t) {
#pragma unroll 4
    for (int jj = 0; jj < 8; ++jj) {
      int j = w * 8 + jj;
      short8 v;
#pragma unroll
      for (int e = 0; e < 8; ++e) {
        float f = lat[((size_t)(b * D_ + j * 8 + e)) * HW_ + hwb + t * 64 + lane];
        v[e] = (short)f2bf(f);
      }
      int row = t * 64 + lane;
      *(short8*)&img[row * 256 + ((j * 8) ^ ((row & 15) << 4))] = v;
    }
  }
  __syncthreads();

  // ---- extract B-frags + |f|^2 (waves 2pg,2pg+1 read rows pg*64..) ----
  short8 bfrag[4][8];
  float fn[4];
#pragma unroll
  for (int pf = 0; pf < 4; ++pf) {
    int row = pg * 64 + pf * 16 + c;
#pragma unroll
    for (int kk = 0; kk < 8; ++kk) {
      int s = (kk << 2) | q;
      bfrag[pf][kk] =
          *(const short8*)&img[row * 256 + ((s * 8) ^ ((row & 15) << 4))];
    }
    float a = 0.f;
#pragma unroll
    for (int kk = 0; kk < 8; ++kk)
#pragma unroll
      for (int e = 0; e < 8; ++e) {
        float f = bf2f((unsigned short)bfrag[pf][kk][e]);
        a += f * f;
      }
    fn[pf] = a;
  }
#pragma unroll
  for (int pf = 0; pf < 4; ++pf) {
    fn[pf] += __shfl_xor(fn[pf], 16, 64);
    fn[pf] += __shfl_xor(fn[pf], 32, 64);
  }
  __syncthreads();  // staging consumed; slots free for codebook pairs

  // ---- prologue: pair 0 (64 codes, 32KB) -> set 0 (slots 0,1) ----
#pragma unroll
  for (int r = 0; r < 8; ++r)
    async16(&slots[0][r * 256 + tid], cbfrag + (r * 256 + tid));

  float runD[4];
  int runI[4];
#pragma unroll
  for (int pf = 0; pf < 4; ++pf) { runD[pf] = 3.0e38f; runI[pf] = 0x7fffffff; }

  // ---- 16 pair-iters: drain (1-iter slack) -> barrier -> issue i+1 -> MFMA ----
#pragma unroll 1
  for (int i = 0; i < 16; ++i) {
    asm volatile("s_waitcnt vmcnt(0)" ::: "memory");
    __builtin_amdgcn_s_barrier();
    __builtin_amdgcn_sched_barrier(0);
    if (i < 15) {  // set (i+1)&1: its readers (iter i-1) all passed barrier-i
      short8* dst = &slots[((i + 1) & 1) * 2][0];
      const short8* src = cbfrag + (i + 1) * 2048;
#pragma unroll
      for (int r = 0; r < 8; ++r) async16(&dst[r * 256 + tid], src + r * 256 + tid);
    }
    float4v acc[2][4];
#pragma unroll
    for (int g = 0; g < 2; ++g) {
      float4v cn = *(const float4v*)&cnorm_s[i * 64 + g * 32 + ch * 16 + q * 4];
#pragma unroll
      for (int pf = 0; pf < 4; ++pf) acc[g][pf] = cn;
    }
    const short8* base = &slots[(i & 1) * 2][0];  // 2048 short8 contiguous
    __builtin_amdgcn_s_setprio(1);
#pragma unroll
    for (int kk = 0; kk < 8; ++kk) {
      short8 afr[2];
#pragma unroll
      for (int g = 0; g < 2; ++g)
        afr[g] = base[g * 1024 + (ch * 8 + kk) * 64 + lane];
#pragma unroll
      for (int g = 0; g < 2; ++g)
#pragma unroll
        for (int pf = 0; pf < 4; ++pf)
          acc[g][pf] = __builtin_amdgcn_mfma_f32_16x16x32_bf16(
              afr[g], bfrag[pf][kk], acc[g][pf], 0, 0, 0);
    }
    __builtin_amdgcn_s_setprio(0);
    // lane-local scan (g ascending, r ascending => strict < = first occurrence)
#pragma unroll
    for (int g = 0; g < 2; ++g)
#pragma unroll
      for (int pf = 0; pf < 4; ++pf) {
        int cb0 = i * 64 + g * 32 + ch * 16 + q * 4;
#pragma unroll
        for (int r = 0; r < 4; ++r) {
          float dv = acc[g][pf][r];
          if (dv < runD[pf]) { runD[pf] = dv; runI[pf] = cb0 + r; }
        }
      }
  }

  // ---- deferred butterfly + cross-wave (ch) merge; idx + loss ----
#pragma unroll
  for (int pf = 0; pf < 4; ++pf) {
#pragma unroll
    for (int di = 16; di < 64; di <<= 1) {
      float od = __shfl_xor(runD[pf], di, 64);
      int oi = __shfl_xor(runI[pf], di, 64);
      if (od < runD[pf] || (od == runD[pf] && oi < runI[pf])) {
        runD[pf] = od; runI[pf] = oi;
      }
    }
  }
  float selD = q == 0 ? runD[0] : q == 1 ? runD[1] : q == 2 ? runD[2] : runD[3];
  int selI = q == 0 ? runI[0] : q == 1 ? runI[1] : q == 2 ? runI[2] : runI[3];
  float selF = q == 0 ? fn[0] : q == 1 ? fn[1] : q == 2 ? fn[2] : fn[3];
  int p = pg * 64 + q * 16 + c;
  if (ch == 1) { mergeD[p] = selD; mergeI[p] = selI; }
  __syncthreads();
  if (ch == 0) {
    float od = mergeD[p];
    int oi = mergeI[p];
    if (od < selD || (od == selD && oi < selI)) { selD = od; selI = oi; }
    idx_out[blk * 128 + p] = selI;
    float lv = selD + selF;  // ||f - c_best||^2
#pragma unroll
    for (int off = 1; off < 64; off <<= 1) lv += __shfl_xor(lv, off, 64);
    if (lane == 0) part[blk * 2 + pg] = lv;
  }
}

// ---- gather: out[b,d,hw] = cb[idx[hw]][d]; 1024 blocks, 4 blocks/CU ----
__global__ __launch_bounds__(256) void vq_gather(const float* __restrict__ cb,
                                                 const int* __restrict__ idx,
                                                 float* __restrict__ out) {
  __shared__ unsigned short gimg[16384];  // 64 rows x 512B, swizzled (32KB)
  __shared__ int sidx[64];
  const int tid = threadIdx.x;
  const int w = tid >> 6, lane = tid & 63;
  const int pt0 = blockIdx.x * 64;
  const int b = pt0 >> 10, hw0 = pt0 & 1023;
  if (tid < 64) sidx[tid] = idx[pt0 + tid];
  __syncthreads();
  // cooperative: wave reads whole cb rows (1KB float4/instr), bf16 to LDS
#pragma unroll 4
  for (int rp = 0; rp < 16; ++rp) {
    int row = rp * 4 + w;
    int gidx = sidx[row];
    float4v cv = ((const float4v*)(cb + (size_t)gidx * D_))[lane];
    short4v sv;
#pragma unroll
    for (int i = 0; i < 4; ++i) sv[i] = (short)f2bf(cv[i]);
    *(short4v*)&gimg[row * 256 + ((lane * 4) ^ ((row & 15) << 4))] = sv;
  }
  __syncthreads();
  // coalesced [B,D,H,W] stores (fp32 round-trip bf16 << threshold)
#pragma unroll
  for (int jo = 0; jo < 8; ++jo) {
    int j = w * 8 + jo;
    short8 v = *(const short8*)&gimg[lane * 256 + ((j * 8) ^ ((lane & 15) << 4))];
#pragma unroll
    for (int e = 0; e < 8; ++e)
      out[((size_t)(b * D_ + j * 8 + e)) * HW_ + hw0 + lane] =
          bf2f((unsigned short)v[e]);
  }
}

// ---- finalize: loss = 1.25 * mean (1024 partials) ----
__global__ __launch_bounds__(256) void vq_fin(const float* __restrict__ part,
                                              float* __restrict__ outs) {
  int t = threadIdx.x;
  float s = part[t] + part[t + 256] + part[t + 512] + part[t + 768];
#pragma unroll
  for (int off = 1; off < 64; off <<= 1) s += __shfl_xor(s, off, 64);
  __shared__ float w4[4];
  if ((t & 63) == 0) w4[t >> 6] = s;
  __syncthreads();
  if (t == 0) *outs = (w4[0] + w4[1] + w4[2] + w4[3]) * (1.25f / 16777216.0f);
}

extern "C" void kernel_launch(void* const* d_in, const int* in_sizes, int n_in,
                              void* d_out, int out_size, void* d_ws, size_t ws_size,
                              hipStream_t stream) {
  const float* lat = (const float*)d_in[0];
  const float* cb = (const float*)d_in[1];
  float* out = (float*)d_out;
  char* ws = (char*)d_ws;
  unsigned short* cbfrag = (unsigned short*)ws;  // 512 KB (bf16 -2c frag image)
  float* cnorm = (float*)(ws + 524288);          // 4 KB
  int* idxbuf = (int*)(ws + 528384);             // 256 KB
  float* partial = (float*)(ws + 790528);        // 4 KB (1024 floats)

  vq_prep<<<1024, 256, 0, stream>>>(cb, cbfrag, cnorm);
  vq_main<<<512, 256, 0, stream>>>(lat, (const short8*)cbfrag, cnorm, idxbuf,
                                   partial);
  vq_gather<<<1024, 256, 0, stream>>>(cb, idxbuf, out);
  vq_fin<<<1, 256, 0, stream>>>(partial, out + 16777216);
}

// Round 16
// 63.934 us; speedup vs baseline: 1.4933x; 1.0525x over previous
//
#include <hip/hip_runtime.h>
#include <hip/hip_bf16.h>

#define D_ 256
#define HW_ 1024

typedef short short4v __attribute__((ext_vector_type(4)));
typedef short short8 __attribute__((ext_vector_type(8)));
typedef float float4v __attribute__((ext_vector_type(4)));

__device__ __forceinline__ unsigned short f2bf(float f) {
  unsigned u = __builtin_bit_cast(unsigned, f);
  return (unsigned short)((u + 0x7fffu + ((u >> 16) & 1u)) >> 16);
}
__device__ __forceinline__ float bf2f(unsigned short h) {
  return __builtin_bit_cast(float, ((unsigned)h) << 16);
}

__device__ __forceinline__ void async16(void* lds, const void* g) {
  __builtin_amdgcn_global_load_lds(
      (__attribute__((address_space(1))) const unsigned int*)g,
      (__attribute__((address_space(3))) unsigned int*)lds, 16, 0, 0);
}

// ---- prep: cnorm + bf16(-2c) in MFMA A-fragment order ----
// cbfrag[((g*8)+kk)*64 + q*16 + cc] (short8) = code g*16+cc, feats kk*32+q*8..+7
__global__ __launch_bounds__(256) void vq_prep(const float* __restrict__ cb,
                                               unsigned short* __restrict__ cbfrag,
                                               float* __restrict__ cnorm) {
  int k = blockIdx.x;   // code 0..1023
  int t = threadIdx.x;  // feature 0..255
  float c = cb[k * D_ + t];
  float s = c * c;
#pragma unroll
  for (int off = 1; off < 64; off <<= 1) s += __shfl_xor(s, off, 64);
  __shared__ float wsum[4];
  if ((t & 63) == 0) wsum[t >> 6] = s;
  __syncthreads();
  if (t == 0) cnorm[k] = wsum[0] + wsum[1] + wsum[2] + wsum[3];
  int g = k >> 4, cc = k & 15;
  int kk = t >> 5, q = (t >> 3) & 3, e = t & 7;
  cbfrag[(((g * 8) + kk) * 64 + q * 16 + cc) * 8 + e] = f2bf(-2.0f * c);
}

// ---- main: counted-vmcnt pipelined distance loop (T3+T4+T5) ----
// 512 blocks x 256 thr (4 waves = 2 pg x 2 ch), 128 pts/block.
// 32-code chunks in 4 x 16KB LDS slots, prefetch 3 ahead, vmcnt(8) steady-state.
__global__ __launch_bounds__(256) void vq_main(const float* __restrict__ lat,
                                               const short8* __restrict__ cbfrag,
                                               const float* __restrict__ cnorm,
                                               int* __restrict__ idx_out,
                                               float* __restrict__ part) {
  __shared__ short8 slots[4][1024];   // 64KB: point tiles first, then cb slots
  __shared__ float cnorm_s[1024];     // 4KB (keeps global loads out of the loop)
  __shared__ float mergeD[128];
  __shared__ int mergeI[128];

  const int tid = threadIdx.x;
  const int w = tid >> 6, lane = tid & 63;
  const int pg = w >> 1, ch = w & 1;
  const int q = lane >> 4, c = lane & 15;
  const int blk = blockIdx.x;
  const int b = blk >> 3, hwb = (blk & 7) << 7;

  cnorm_s[tid] = cnorm[tid];
  cnorm_s[tid + 256] = cnorm[tid + 256];
  cnorm_s[tid + 512] = cnorm[tid + 512];
  cnorm_s[tid + 768] = cnorm[tid + 768];

  // ---- stage 128 pts (coalesced loads, conflict-free b128 swizzled writes) ----
  unsigned short* img = (unsigned short*)&slots[0][0];  // 128 rows x 512B
#pragma unroll 1
  for (int t = 0; t < 2; ++t) {
#pragma unroll 4
    for (int jj = 0; jj < 8; ++jj) {
      int j = w * 8 + jj;
      short8 v;
#pragma unroll
      for (int e = 0; e < 8; ++e) {
        float f = lat[((size_t)(b * D_ + j * 8 + e)) * HW_ + hwb + t * 64 + lane];
        v[e] = (short)f2bf(f);
      }
      int row = t * 64 + lane;
      *(short8*)&img[row * 256 + ((j * 8) ^ ((row & 15) << 4))] = v;
    }
  }
  __syncthreads();

  // ---- extract B-frags + |f|^2 (waves 2pg,2pg+1 read rows pg*64..) ----
  short8 bfrag[4][8];
  float fn[4];
#pragma unroll
  for (int pf = 0; pf < 4; ++pf) {
    int row = pg * 64 + pf * 16 + c;
#pragma unroll
    for (int kk = 0; kk < 8; ++kk) {
      int s = (kk << 2) | q;
      bfrag[pf][kk] =
          *(const short8*)&img[row * 256 + ((s * 8) ^ ((row & 15) << 4))];
    }
    float a = 0.f;
#pragma unroll
    for (int kk = 0; kk < 8; ++kk)
#pragma unroll
      for (int e = 0; e < 8; ++e) {
        float f = bf2f((unsigned short)bfrag[pf][kk][e]);
        a += f * f;
      }
    fn[pf] = a;
  }
#pragma unroll
  for (int pf = 0; pf < 4; ++pf) {
    fn[pf] += __shfl_xor(fn[pf], 16, 64);
    fn[pf] += __shfl_xor(fn[pf], 32, 64);
  }
  __syncthreads();  // tiles consumed (drains lgkm); slots free for codebook

  // ---- prologue: issue chunks 0,1,2 into slots 0,1,2 (12 outstanding) ----
#pragma unroll
  for (int ck = 0; ck < 3; ++ck)
#pragma unroll
    for (int r = 0; r < 4; ++r)
      async16(&slots[ck][r * 256 + tid], cbfrag + (ck * 1024 + r * 256 + tid));

  float runD[4];
  int runI[4];
#pragma unroll
  for (int pf = 0; pf < 4; ++pf) { runD[pf] = 3.0e38f; runI[pf] = 0x7fffffff; }

  // ---- 32 chunks; per iter: counted wait -> barrier -> MFMA -> issue i+3 ----
#pragma unroll 1
  for (int i = 0; i < 32; ++i) {
    if (i < 30) asm volatile("s_waitcnt vmcnt(8)" ::: "memory");
    else if (i == 30) asm volatile("s_waitcnt vmcnt(4)" ::: "memory");
    else asm volatile("s_waitcnt vmcnt(0)" ::: "memory");
    __builtin_amdgcn_s_barrier();
    __builtin_amdgcn_sched_barrier(0);

    float4v cn = *(const float4v*)&cnorm_s[i * 32 + ch * 16 + q * 4];
    float4v acc[4];
#pragma unroll
    for (int pf = 0; pf < 4; ++pf) acc[pf] = cn;
    const short8* slot = &slots[i & 3][0];
    __builtin_amdgcn_s_setprio(1);
#pragma unroll
    for (int kk = 0; kk < 8; ++kk) {
      short8 afr = slot[(ch * 8 + kk) * 64 + lane];
#pragma unroll
      for (int pf = 0; pf < 4; ++pf)
        acc[pf] = __builtin_amdgcn_mfma_f32_16x16x32_bf16(afr, bfrag[pf][kk],
                                                          acc[pf], 0, 0, 0);
    }
    __builtin_amdgcn_s_setprio(0);
    __builtin_amdgcn_sched_barrier(0);

    // lane-local scan (ascending code index; strict < = first occurrence)
#pragma unroll
    for (int pf = 0; pf < 4; ++pf) {
      int cb0 = i * 32 + ch * 16 + q * 4;
#pragma unroll
      for (int r = 0; r < 4; ++r) {
        float dv = acc[pf][r];
        if (dv < runD[pf]) { runD[pf] = dv; runI[pf] = cb0 + r; }
      }
    }
    if (i < 29) {
      int ck = i + 3;
      short8* dst = &slots[ck & 3][0];
      const short8* src = cbfrag + ck * 1024;
#pragma unroll
      for (int r = 0; r < 4; ++r) async16(&dst[r * 256 + tid], src + r * 256 + tid);
    }
  }

  // ---- deferred butterfly + cross-wave (ch) merge; idx + loss ----
#pragma unroll
  for (int pf = 0; pf < 4; ++pf) {
#pragma unroll
    for (int di = 16; di < 64; di <<= 1) {
      float od = __shfl_xor(runD[pf], di, 64);
      int oi = __shfl_xor(runI[pf], di, 64);
      if (od < runD[pf] || (od == runD[pf] && oi < runI[pf])) {
        runD[pf] = od; runI[pf] = oi;
      }
    }
  }
  float selD = q == 0 ? runD[0] : q == 1 ? runD[1] : q == 2 ? runD[2] : runD[3];
  int selI = q == 0 ? runI[0] : q == 1 ? runI[1] : q == 2 ? runI[2] : runI[3];
  float selF = q == 0 ? fn[0] : q == 1 ? fn[1] : q == 2 ? fn[2] : fn[3];
  int p = pg * 64 + q * 16 + c;
  if (ch == 1) { mergeD[p] = selD; mergeI[p] = selI; }
  __syncthreads();
  if (ch == 0) {
    float od = mergeD[p];
    int oi = mergeI[p];
    if (od < selD || (od == selD && oi < selI)) { selD = od; selI = oi; }
    idx_out[blk * 128 + p] = selI;
    float lv = selD + selF;  // ||f - c_best||^2
#pragma unroll
    for (int off = 1; off < 64; off <<= 1) lv += __shfl_xor(lv, off, 64);
    if (lane == 0) part[blk * 2 + pg] = lv;
  }
}

// ---- gather: out[b,d,hw] = cb[idx[hw]][d]; 1024 blocks, 4 blocks/CU ----
__global__ __launch_bounds__(256) void vq_gather(const float* __restrict__ cb,
                                                 const int* __restrict__ idx,
                                                 float* __restrict__ out) {
  __shared__ unsigned short gimg[16384];  // 64 rows x 512B, swizzled (32KB)
  __shared__ int sidx[64];
  const int tid = threadIdx.x;
  const int w = tid >> 6, lane = tid & 63;
  const int pt0 = blockIdx.x * 64;
  const int b = pt0 >> 10, hw0 = pt0 & 1023;
  if (tid < 64) sidx[tid] = idx[pt0 + tid];
  __syncthreads();
  // cooperative: wave reads whole cb rows (1KB float4/instr), bf16 to LDS
#pragma unroll 4
  for (int rp = 0; rp < 16; ++rp) {
    int row = rp * 4 + w;
    int gidx = sidx[row];
    float4v cv = ((const float4v*)(cb + (size_t)gidx * D_))[lane];
    short4v sv;
#pragma unroll
    for (int i = 0; i < 4; ++i) sv[i] = (short)f2bf(cv[i]);
    *(short4v*)&gimg[row * 256 + ((lane * 4) ^ ((row & 15) << 4))] = sv;
  }
  __syncthreads();
  // coalesced [B,D,H,W] stores (fp32 values round-trip bf16: << threshold)
#pragma unroll
  for (int jo = 0; jo < 8; ++jo) {
    int j = w * 8 + jo;
    short8 v = *(const short8*)&gimg[lane * 256 + ((j * 8) ^ ((lane & 15) << 4))];
#pragma unroll
    for (int e = 0; e < 8; ++e)
      out[((size_t)(b * D_ + j * 8 + e)) * HW_ + hw0 + lane] =
          bf2f((unsigned short)v[e]);
  }
}

// ---- finalize: loss = 1.25 * mean (1024 partials) ----
__global__ __launch_bounds__(256) void vq_fin(const float* __restrict__ part,
                                              float* __restrict__ outs) {
  int t = threadIdx.x;
  float s = part[t] + part[t + 256] + part[t + 512] + part[t + 768];
#pragma unroll
  for (int off = 1; off < 64; off <<= 1) s += __shfl_xor(s, off, 64);
  __shared__ float w4[4];
  if ((t & 63) == 0) w4[t >> 6] = s;
  __syncthreads();
  if (t == 0) *outs = (w4[0] + w4[1] + w4[2] + w4[3]) * (1.25f / 16777216.0f);
}

extern "C" void kernel_launch(void* const* d_in, const int* in_sizes, int n_in,
                              void* d_out, int out_size, void* d_ws, size_t ws_size,
                              hipStream_t stream) {
  const float* lat = (const float*)d_in[0];
  const float* cb = (const float*)d_in[1];
  float* out = (float*)d_out;
  char* ws = (char*)d_ws;
  unsigned short* cbfrag = (unsigned short*)ws;  // 512 KB (bf16 -2c frag image)
  float* cnorm = (float*)(ws + 524288);          // 4 KB
  int* idxbuf = (int*)(ws + 528384);             // 256 KB
  float* partial = (float*)(ws + 790528);        // 4 KB (1024 floats)

  vq_prep<<<1024, 256, 0, stream>>>(cb, cbfrag, cnorm);
  vq_main<<<512, 256, 0, stream>>>(lat, (const short8*)cbfrag, cnorm, idxbuf,
                                   partial);
  vq_gather<<<1024, 256, 0, stream>>>(cb, idxbuf, out);
  vq_fin<<<1, 256, 0, stream>>>(partial, out + 16777216);
}